// Round 1
// baseline (30.683 us; speedup 1.0000x reference)
//
#include <hip/hip_runtime.h>
#include <hip/hip_bf16.h>

#define VOCAB 100000
#define EMB 300
#define BATCH 2048
#define SEQ 256

// Kernel 1: p[v] = dot(W_emb[v, :], fc_w[:])  for v in [0, VOCAB)
// One wave (64 lanes) per row; rows are 300 floats = 75 float4 (16B aligned
// since 300 % 4 == 0). Lanes 0..63 read float4 idx 0..63, lanes 0..10 also
// read idx 64..74. Shuffle-reduce width 64, lane 0 writes.
__global__ void __launch_bounds__(256) vocab_dot_kernel(
    const float* __restrict__ W, const float* __restrict__ fcw,
    float* __restrict__ p, int nrows) {
  const int lane = threadIdx.x & 63;
  const int wave = (blockIdx.x * blockDim.x + threadIdx.x) >> 6;
  const int nwaves = (gridDim.x * blockDim.x) >> 6;

  const float4* fcw4 = (const float4*)fcw;
  float4 wa = fcw4[lane];                                   // idx 0..63
  float4 wb = make_float4(0.f, 0.f, 0.f, 0.f);
  if (lane < 11) wb = fcw4[64 + lane];                      // idx 64..74

  for (int v = wave; v < nrows; v += nwaves) {
    const float4* row = (const float4*)(W + (size_t)v * EMB);
    float4 a = row[lane];
    float acc = a.x * wa.x + a.y * wa.y + a.z * wa.z + a.w * wa.w;
    if (lane < 11) {
      float4 b4 = row[64 + lane];
      acc += b4.x * wb.x + b4.y * wb.y + b4.z * wb.z + b4.w * wb.w;
    }
    #pragma unroll
    for (int off = 32; off > 0; off >>= 1)
      acc += __shfl_down(acc, off, 64);
    if (lane == 0) p[v] = acc;
  }
}

// Kernel 2: out[b] = sigmoid( (sum_{l<len} p[tok[b,l]]) / len + fc_b )
// One wave per item (<=4 gathered loads per lane from the 400 KB p table).
__global__ void __launch_bounds__(256) pool_sigmoid_kernel(
    const int* __restrict__ tokens, const int* __restrict__ lengths,
    const float* __restrict__ p, const float* __restrict__ fcb,
    float* __restrict__ out, int B, int L) {
  const int lane = threadIdx.x & 63;
  const int wib = threadIdx.x >> 6;
  const int b = blockIdx.x * (blockDim.x >> 6) + wib;
  if (b >= B) return;

  const int len = lengths[b];
  const int* t = tokens + (size_t)b * L;
  float acc = 0.f;
  for (int l = lane; l < len; l += 64)
    acc += p[t[l]];
  #pragma unroll
  for (int off = 32; off > 0; off >>= 1)
    acc += __shfl_down(acc, off, 64);
  if (lane == 0) {
    float z = acc / (float)len + fcb[0];
    out[b] = 1.0f / (1.0f + expf(-z));
  }
}

extern "C" void kernel_launch(void* const* d_in, const int* in_sizes, int n_in,
                              void* d_out, int out_size, void* d_ws, size_t ws_size,
                              hipStream_t stream) {
  const int*   tokens  = (const int*)d_in[0];    // [B, L]
  const int*   lengths = (const int*)d_in[1];    // [B]
  const float* W_emb   = (const float*)d_in[2];  // [VOCAB, EMB]
  const float* fc_w    = (const float*)d_in[3];  // [1, EMB]
  const float* fc_b    = (const float*)d_in[4];  // [1]
  float* out = (float*)d_out;                    // [B, 1]
  float* p   = (float*)d_ws;                     // VOCAB floats (400 KB)

  // Kernel 1: 2048 blocks x 256 threads = 8192 waves, grid-stride over rows.
  vocab_dot_kernel<<<2048, 256, 0, stream>>>(W_emb, fc_w, p, VOCAB);

  // Kernel 2: 4 waves/block -> BATCH/4 blocks, one wave per item.
  pool_sigmoid_kernel<<<BATCH / 4, 256, 0, stream>>>(
      tokens, lengths, p, fc_b, out, BATCH, SEQ);
}

// Round 2
// 27.565 us; speedup vs baseline: 1.1131x; 1.1131x over previous
//
#include <hip/hip_runtime.h>
#include <hip/hip_bf16.h>

#define VOCAB 100000
#define EMB 300
#define BATCH 2048
#define SEQ 256

// Kernel 1: p[v] = dot(W_emb[v, :], fc_w[:])  for v in [0, VOCAB)
// One wave (64 lanes) per row, 2 rows per iteration for MLP; rows are 300
// floats = 75 float4 (16B-aligned since 300 % 4 == 0). Lanes 0..63 read
// float4 idx 0..63, lanes 0..10 also read idx 64..74. Shuffle-reduce 64.
__global__ void __launch_bounds__(256) vocab_dot_kernel(
    const float* __restrict__ W, const float* __restrict__ fcw,
    float* __restrict__ p, int nrows) {
  const int lane = threadIdx.x & 63;
  const int wave = (blockIdx.x * blockDim.x + threadIdx.x) >> 6;
  const int nwaves = (gridDim.x * blockDim.x) >> 6;

  const float4* fcw4 = (const float4*)fcw;
  float4 wa = fcw4[lane];                                   // idx 0..63
  float4 wb = make_float4(0.f, 0.f, 0.f, 0.f);
  if (lane < 11) wb = fcw4[64 + lane];                      // idx 64..74

  for (int v = wave * 2; v < nrows; v += nwaves * 2) {
    const float4* r0 = (const float4*)(W + (size_t)v * EMB);
    // Issue all independent loads up front (2 rows x {main, tail}).
    float4 a0 = r0[lane];
    float4 t0 = (lane < 11) ? r0[64 + lane] : make_float4(0.f, 0.f, 0.f, 0.f);
    float4 a1 = make_float4(0.f, 0.f, 0.f, 0.f);
    float4 t1 = make_float4(0.f, 0.f, 0.f, 0.f);
    const bool has1 = (v + 1) < nrows;
    if (has1) {
      const float4* r1 = (const float4*)(W + (size_t)(v + 1) * EMB);
      a1 = r1[lane];
      if (lane < 11) t1 = r1[64 + lane];
    }

    float acc0 = a0.x * wa.x + a0.y * wa.y + a0.z * wa.z + a0.w * wa.w
               + t0.x * wb.x + t0.y * wb.y + t0.z * wb.z + t0.w * wb.w;
    float acc1 = a1.x * wa.x + a1.y * wa.y + a1.z * wa.z + a1.w * wa.w
               + t1.x * wb.x + t1.y * wb.y + t1.z * wb.z + t1.w * wb.w;

    #pragma unroll
    for (int off = 32; off > 0; off >>= 1) {
      acc0 += __shfl_down(acc0, off, 64);
      acc1 += __shfl_down(acc1, off, 64);
    }
    if (lane == 0) {
      p[v] = acc0;
      if (has1) p[v + 1] = acc1;
    }
  }
}

// Kernel 2: out[b] = sigmoid( (sum_{l<len} p[tok[b,l]]) / len + fc_b )
// One block (256 threads) per item; thread t handles position t (L == 256).
__global__ void __launch_bounds__(256) pool_sigmoid_kernel(
    const int* __restrict__ tokens, const int* __restrict__ lengths,
    const float* __restrict__ p, const float* __restrict__ fcb,
    float* __restrict__ out, int L) {
  __shared__ float part[4];
  const int b = blockIdx.x;
  const int t = threadIdx.x;
  const int len = lengths[b];

  float acc = 0.f;
  if (t < len) acc = p[tokens[(size_t)b * L + t]];

  #pragma unroll
  for (int off = 32; off > 0; off >>= 1)
    acc += __shfl_down(acc, off, 64);

  const int lane = t & 63, w = t >> 6;
  if (lane == 0) part[w] = acc;
  __syncthreads();
  if (t == 0) {
    float s = part[0] + part[1] + part[2] + part[3];
    float z = s / (float)len + fcb[0];
    out[b] = 1.0f / (1.0f + expf(-z));
  }
}

extern "C" void kernel_launch(void* const* d_in, const int* in_sizes, int n_in,
                              void* d_out, int out_size, void* d_ws, size_t ws_size,
                              hipStream_t stream) {
  const int*   tokens  = (const int*)d_in[0];    // [B, L]
  const int*   lengths = (const int*)d_in[1];    // [B]
  const float* W_emb   = (const float*)d_in[2];  // [VOCAB, EMB]
  const float* fc_w    = (const float*)d_in[3];  // [1, EMB]
  const float* fc_b    = (const float*)d_in[4];  // [1]
  float* out = (float*)d_out;                    // [B, 1]
  float* p   = (float*)d_ws;                     // VOCAB floats (400 KB)

  // Kernel 1: 2048 blocks x 256 threads = 8192 waves, 2 rows per iteration.
  vocab_dot_kernel<<<2048, 256, 0, stream>>>(W_emb, fc_w, p, VOCAB);

  // Kernel 2: one block per item.
  pool_sigmoid_kernel<<<BATCH, 256, 0, stream>>>(
      tokens, lengths, p, fc_b, out, SEQ);
}

// Round 3
// 26.919 us; speedup vs baseline: 1.1398x; 1.0240x over previous
//
#include <hip/hip_runtime.h>
#include <hip/hip_bf16.h>

#define VOCAB 100000
#define EMB 300
#define BATCH 2048
#define SEQ 256

typedef float f4 __attribute__((ext_vector_type(4)));

// Kernel 1: p[v] = dot(W_emb[v, :], fc_w[:])  for v in [0, VOCAB)
// 16 lanes per row, 4 rows per wave per iteration. Row = 75 float4
// (16B-aligned, 300 % 4 == 0). Lane i of group g reads float4 idx
// {i, i+16, i+32, i+48} (+ i+64 if i<11) of row v0+g. One 4-step
// __shfl_xor width-16 reduce sums all four rows simultaneously.
__global__ void __launch_bounds__(256) vocab_dot_kernel(
    const float* __restrict__ W, const float* __restrict__ fcw,
    float* __restrict__ p, int nrows) {
  const int lane = threadIdx.x & 63;
  const int g    = lane >> 4;        // group 0..3 (row within quad)
  const int i    = lane & 15;        // lane within group
  const int wave = (blockIdx.x * blockDim.x + threadIdx.x) >> 6;
  const int nwaves = (gridDim.x * blockDim.x) >> 6;

  const f4* fcw4 = (const f4*)fcw;
  const f4 zero = (f4){0.f, 0.f, 0.f, 0.f};
  f4 w0 = fcw4[i];
  f4 w1 = fcw4[i + 16];
  f4 w2 = fcw4[i + 32];
  f4 w3 = fcw4[i + 48];
  f4 w4 = (i < 11) ? fcw4[i + 64] : zero;

  for (int v0 = wave * 4; v0 < nrows; v0 += nwaves * 4) {
    const int v = v0 + g;
    float acc = 0.f;
    if (v < nrows) {
      const f4* r = (const f4*)(W + (size_t)v * EMB);
      f4 a0 = __builtin_nontemporal_load(&r[i]);
      f4 a1 = __builtin_nontemporal_load(&r[i + 16]);
      f4 a2 = __builtin_nontemporal_load(&r[i + 32]);
      f4 a3 = __builtin_nontemporal_load(&r[i + 48]);
      f4 a4 = (i < 11) ? __builtin_nontemporal_load(&r[i + 64]) : zero;
      f4 s = a0 * w0 + a1 * w1 + a2 * w2 + a3 * w3 + a4 * w4;
      acc = s.x + s.y + s.z + s.w;
    }
    // Segmented reduce: sums within each 16-lane group (all 4 rows at once).
    acc += __shfl_xor(acc, 8, 16);
    acc += __shfl_xor(acc, 4, 16);
    acc += __shfl_xor(acc, 2, 16);
    acc += __shfl_xor(acc, 1, 16);
    if (i == 0 && v < nrows) p[v] = acc;
  }
}

// Kernel 2: out[b] = sigmoid( (sum_{l<len} p[tok[b,l]]) / len + fc_b )
// One block (256 threads) per item; thread t handles position t (L == 256).
__global__ void __launch_bounds__(256) pool_sigmoid_kernel(
    const int* __restrict__ tokens, const int* __restrict__ lengths,
    const float* __restrict__ p, const float* __restrict__ fcb,
    float* __restrict__ out, int L) {
  __shared__ float part[4];
  const int b = blockIdx.x;
  const int t = threadIdx.x;
  const int len = lengths[b];

  float acc = 0.f;
  if (t < len) acc = p[tokens[(size_t)b * L + t]];

  #pragma unroll
  for (int off = 32; off > 0; off >>= 1)
    acc += __shfl_down(acc, off, 64);

  const int lane = t & 63, w = t >> 6;
  if (lane == 0) part[w] = acc;
  __syncthreads();
  if (t == 0) {
    float s = part[0] + part[1] + part[2] + part[3];
    float z = s / (float)len + fcb[0];
    out[b] = 1.0f / (1.0f + expf(-z));
  }
}

extern "C" void kernel_launch(void* const* d_in, const int* in_sizes, int n_in,
                              void* d_out, int out_size, void* d_ws, size_t ws_size,
                              hipStream_t stream) {
  const int*   tokens  = (const int*)d_in[0];    // [B, L]
  const int*   lengths = (const int*)d_in[1];    // [B]
  const float* W_emb   = (const float*)d_in[2];  // [VOCAB, EMB]
  const float* fc_w    = (const float*)d_in[3];  // [1, EMB]
  const float* fc_b    = (const float*)d_in[4];  // [1]
  float* out = (float*)d_out;                    // [B, 1]
  float* p   = (float*)d_ws;                     // VOCAB floats (400 KB)

  // Kernel 1: 2048 blocks x 256 threads = 8192 waves, 4 rows/wave/iter.
  vocab_dot_kernel<<<2048, 256, 0, stream>>>(W_emb, fc_w, p, VOCAB);

  // Kernel 2: one block per item.
  pool_sigmoid_kernel<<<BATCH, 256, 0, stream>>>(
      tokens, lengths, p, fc_b, out, SEQ);
}